// Round 6
// baseline (1331.448 us; speedup 1.0000x reference)
//
#include <hip/hip_runtime.h>
#include <hip/hip_bf16.h>

#define TOKENS 2048
#define HDIM   2560
#define NEXP   16
#define IDIM   1664
#define ISDIM  3328
#define NPAIR  (TOKENS*2)

typedef float  f32x4   __attribute__((ext_vector_type(4)));
typedef __bf16 bf16x8  __attribute__((ext_vector_type(8)));
typedef short  short8v __attribute__((ext_vector_type(8)));

__device__ __forceinline__ short f2bf(float f) {
  unsigned u = __builtin_bit_cast(unsigned, f);
  u += 0x7FFFu + ((u >> 16) & 1u);          // RNE to bf16
  return (short)(u >> 16);
}

// barrier without vmcnt(0): ds-writes drained, in-flight global loads kept
#define BAR() do { \
    asm volatile("s_waitcnt lgkmcnt(0)" ::: "memory"); \
    __builtin_amdgcn_sched_barrier(0); \
    __builtin_amdgcn_s_barrier(); \
    __builtin_amdgcn_sched_barrier(0); \
  } while (0)

// ---------------- router: fp32 logits, softmax-top2-renorm == sigmoid(l0-l1)
__global__ void router_kernel(const float* __restrict__ x, const float* __restrict__ rw,
                              int* __restrict__ counts, int* __restrict__ tidx,
                              float* __restrict__ tw) {
  const int t = blockIdx.x;
  const int lane = threadIdx.x;
  float acc[NEXP];
#pragma unroll
  for (int e = 0; e < NEXP; ++e) acc[e] = 0.f;
  const float* xr = x + (size_t)t * HDIM;
  for (int k = lane; k < HDIM; k += 64) {
    float xv = xr[k];
#pragma unroll
    for (int e = 0; e < NEXP; ++e) acc[e] += xv * rw[e * HDIM + k];
  }
#pragma unroll
  for (int e = 0; e < NEXP; ++e) {
#pragma unroll
    for (int o = 32; o > 0; o >>= 1) acc[e] += __shfl_down(acc[e], o);
  }
  if (lane == 0) {
    int i0 = 0; float v0 = acc[0];
#pragma unroll
    for (int e = 1; e < NEXP; ++e) if (acc[e] > v0) { v0 = acc[e]; i0 = e; }
    int i1 = -1; float v1 = -3.4e38f;
#pragma unroll
    for (int e = 0; e < NEXP; ++e) if (e != i0 && acc[e] > v1) { v1 = acc[e]; i1 = e; }
    float w0 = 1.f / (1.f + expf(v1 - v0));
    tidx[t * 2] = i0; tidx[t * 2 + 1] = i1;
    tw[t * 2] = w0;   tw[t * 2 + 1] = 1.f - w0;
    atomicAdd(&counts[i0], 1);
    atomicAdd(&counts[i1], 1);
  }
}

__global__ void scan_kernel(const int* __restrict__ counts, int* __restrict__ offsets) {
  if (threadIdx.x == 0) {
    int a = 0;
    for (int e = 0; e < NEXP; ++e) { offsets[e] = a; a += counts[e]; }
  }
}

// ---------------- bucket pairs + gather bf16 activations
__global__ void gather_kernel(const float* __restrict__ x, const int* __restrict__ tidx,
                              const float* __restrict__ tw, const int* __restrict__ offsets,
                              int* __restrict__ slotc, int* __restrict__ pairpos,
                              float* __restrict__ wrow, short* __restrict__ xb,
                              short* __restrict__ xg) {
  const int t = blockIdx.x, tid = threadIdx.x;
  __shared__ int grs[2];
  if (tid < 2) {
    int e = tidx[t * 2 + tid];
    int slot = atomicAdd(&slotc[e], 1);
    int g = offsets[e] + slot;
    grs[tid] = g;
    pairpos[t * 2 + tid] = g;
    wrow[g] = tw[t * 2 + tid];
  }
  __syncthreads();
  const int g0 = grs[0], g1 = grs[1];
  const float* xr = x + (size_t)t * HDIM;
#pragma unroll
  for (int i = 0; i < HDIM / 256; ++i) {
    int k = tid + i * 256;
    short v = f2bf(xr[k]);
    xb[(size_t)t * HDIM + k] = v;
    xg[(size_t)g0 * HDIM + k] = v;
    xg[(size_t)g1 * HDIM + k] = v;
  }
}

// ================= merged UP: H = bf16( silu(A*B1) * (A*B3) )
// A bf16 (M,K=2560) K-contig; B fp32 (K,N) N-contig.  BM=128, BN=64, BK=32.
// 256 threads, 4 waves (4 in M), wave tile 32x64.
// Depth-2 register pipeline: tile k+2 loading, k+1 LDS-writing, k computing.
// Raw lgkmcnt(0)+s_barrier (no vmcnt drain) — compiler counts vmcnt at reg use.
__launch_bounds__(256, 2)
__global__ void moe_up_k(const short* __restrict__ xg, const short* __restrict__ xb,
                         const float* __restrict__ w1, const float* __restrict__ w3,
                         const float* __restrict__ sg, const float* __restrict__ su,
                         short* __restrict__ hbE, short* __restrict__ hbS,
                         const int* __restrict__ counts, const int* __restrict__ offsets) {
  const int tid = threadIdx.x;
  const int lin = blockIdx.x;
  const short* A; const float* B1; const float* B3; short* H;
  int N, mtile, ntile, rowbase = 0, cnt = 0x7fffffff;
  bool expert;
  if (lin < 26 * 32 * NEXP) {
    // 13312 = 8 XCD x 1664; m fastest -> m-siblings of an (e,n) adjacent (L2)
    int idx = (lin & 7) * 1664 + (lin >> 3);
    int m = idx & 31;
    int rest = idx >> 5;          // 0..415
    int n = rest % 26;
    int e = rest / 26;
    cnt = counts[e];
    mtile = m * 128;
    if (mtile >= cnt) return;
    rowbase = offsets[e];
    A = xg; B1 = w1 + (size_t)e * HDIM * IDIM; B3 = w3 + (size_t)e * HDIM * IDIM;
    H = hbE; N = IDIM; ntile = n * 64; expert = true;
  } else {
    int s = lin - 26 * 32 * NEXP;   // 0..831
    int n = s % 52;
    int m = s / 52;                 // 0..15
    mtile = m * 128;
    A = xb; B1 = sg; B3 = su; H = hbS; N = ISDIM; ntile = n * 64; expert = false;
  }
  const int K = HDIM;
  const int KT = HDIM / 32;         // 80, even

  __shared__ short Ab[2][128][32];       // 8 KB x2, linear (row=tid>>2, unit=tid&3)
  __shared__ short Bb[2][2][64][32];     // 4 KB x2mat x2buf, swizzled [n][k]

  f32x4 accG[2][4], accU[2][4];
#pragma unroll
  for (int i = 0; i < 2; ++i)
#pragma unroll
    for (int j = 0; j < 4; ++j) { f32x4 z = {0.f,0.f,0.f,0.f}; accG[i][j] = z; accU[i][j] = z; }

  int a_gr[2];
#pragma unroll
  for (int p = 0; p < 2; ++p) {
    int row = ((tid + (p << 8)) >> 2);
    int gr = expert ? (rowbase + mtile + row) : (mtile + row);
    if (gr > NPAIR - 1) gr = NPAIR - 1;
    a_gr[p] = gr;
  }
  const int a_ko = (tid & 3) << 3;

  const int b_sm = tid >> 7;
  const int b_n  = tid & 63;
  const int b_oh = (tid >> 6) & 1;
  const float* Bs = b_sm ? B3 : B1;
  const float* b_base = Bs + ntile + b_n;

  int4  aR0[2], aR1[2];
  float bR0[16], bR1[16];

  auto loadA = [&](int kt, int4* aR) {
#pragma unroll
    for (int p = 0; p < 2; ++p)
      aR[p] = *reinterpret_cast<const int4*>(A + (size_t)a_gr[p] * K + (kt << 5) + a_ko);
  };
  auto loadB = [&](int kt, float* bR) {
    const float* p = b_base + (size_t)(kt << 5) * N;
#pragma unroll
    for (int op = 0; op < 2; ++op)
#pragma unroll
      for (int j = 0; j < 8; ++j)
        bR[op * 8 + j] = p[(size_t)((b_oh * 2 + op) * 8 + j) * N];
  };
  auto writeA = [&](int buf, const int4* aR) {
#pragma unroll
    for (int p = 0; p < 2; ++p)
      *reinterpret_cast<int4*>((short*)Ab[buf] + (size_t)(tid + (p << 8)) * 8) = aR[p];
  };
  auto writeB = [&](int buf, const float* bR) {
#pragma unroll
    for (int op = 0; op < 2; ++op) {
      const int oct = b_oh * 2 + op;
      const int up = oct ^ ((b_n >> 1) & 3);
      short8v s;
#pragma unroll
      for (int j = 0; j < 8; ++j) s[j] = f2bf(bR[op * 8 + j]);
      *reinterpret_cast<short8v*>(&Bb[buf][b_sm][b_n][up << 3]) = s;
    }
  };

  const int lane = tid & 63;
  const int w = tid >> 6;
  const int wm = w * 32;
  const int lrow = lane & 15;
  const int lkg = lane >> 4;

  auto compute = [&](int buf) {
    bf16x8 af[2], bG[4], bU[4];
#pragma unroll
    for (int mf = 0; mf < 2; ++mf)
      af[mf] = *reinterpret_cast<const bf16x8*>(&Ab[buf][wm + mf * 16 + lrow][lkg << 3]);
#pragma unroll
    for (int nf = 0; nf < 4; ++nf) {
      const int n = nf * 16 + lrow;
      const int kg = (lkg ^ ((n >> 1) & 3)) << 3;
      bG[nf] = *reinterpret_cast<const bf16x8*>(&Bb[buf][0][n][kg]);
      bU[nf] = *reinterpret_cast<const bf16x8*>(&Bb[buf][1][n][kg]);
    }
#pragma unroll
    for (int mf = 0; mf < 2; ++mf)
#pragma unroll
      for (int nf = 0; nf < 4; ++nf) {
        accG[mf][nf] = __builtin_amdgcn_mfma_f32_16x16x32_bf16(af[mf], bG[nf], accG[mf][nf], 0, 0, 0);
        accU[mf][nf] = __builtin_amdgcn_mfma_f32_16x16x32_bf16(af[mf], bU[nf], accU[mf][nf], 0, 0, 0);
      }
  };

  // prologue: sets hold tiles 0 (set0) and 1 (set1); buf0 <- tile0
  loadA(0, aR0); loadB(0, bR0);
  loadA(1, aR1); loadB(1, bR1);
  writeA(0, aR0); writeB(0, bR0);
  BAR();
  for (int kt = 0; kt < KT; kt += 2) {
    // even: compute tile kt (buf0); stage tile kt+1 (buf1) from set1; refill set0 with kt+2
    if (kt + 2 < KT) { loadA(kt + 2, aR0); loadB(kt + 2, bR0); }
    compute(0);
    writeA(1, aR1); writeB(1, bR1);
    BAR();
    // odd: compute tile kt+1 (buf1); stage tile kt+2 (buf0) from set0; refill set1 with kt+3
    if (kt + 3 < KT) { loadA(kt + 3, aR1); loadB(kt + 3, bR1); }
    compute(1);
    if (kt + 2 < KT) { writeA(0, aR0); writeB(0, bR0); }
    BAR();
  }

  // epilogue: silu(g)*u -> bf16. C/D: col=lane&15, row=(lane>>4)*4+r
#pragma unroll
  for (int mf = 0; mf < 2; ++mf) {
#pragma unroll
    for (int r = 0; r < 4; ++r) {
      const int rt = wm + mf * 16 + ((lane >> 4) << 2) + r;
      if (expert && mtile + rt >= cnt) continue;
      const size_t grow = (size_t)((expert ? rowbase : 0) + mtile + rt);
      const int colb = ntile + lrow;
#pragma unroll
      for (int nf = 0; nf < 4; ++nf) {
        float g = accG[mf][nf][r];
        float u = accU[mf][nf][r];
        H[grow * N + colb + nf * 16] = f2bf(g / (1.f + expf(-g)) * u);
      }
    }
  }
}

// ================= merged DOWN: Out = A*B.  BM=128, BN=128, BK=32, 256 thr,
// 4 waves (2M x 2N), wave tile 64x64.  Same depth-2 register pipeline.
// expert: A=hbE (K=1664), B=w2[e], out=pairs[gr] (dense, scaled by wrow).
// shared: A=hbS (K=3328), B=sd, out=plain (combine kernel adds pairs).
__launch_bounds__(256, 2)
__global__ void moe_dn_k(const short* __restrict__ hbE, const short* __restrict__ hbS,
                         const float* __restrict__ w2, const float* __restrict__ sd,
                         float* __restrict__ pairs, float* __restrict__ outb,
                         const int* __restrict__ counts, const int* __restrict__ offsets,
                         const float* __restrict__ wrow) {
  const int tid = threadIdx.x;
  const int lin = blockIdx.x;
  const short* A; const float* B; float* Out;
  int K, KT, mtile, ntile, rowbase = 0, cnt = 0x7fffffff;
  bool expert;
  if (lin < 20 * 32 * NEXP) {
    // 10240 = 8 XCD x 1280; m fastest
    int idx = (lin & 7) * 1280 + (lin >> 3);
    int m = idx & 31;
    int rest = idx >> 5;          // 0..319
    int n = rest % 20;
    int e = rest / 20;
    cnt = counts[e];
    mtile = m * 128;
    if (mtile >= cnt) return;
    rowbase = offsets[e];
    A = hbE; B = w2 + (size_t)e * IDIM * HDIM;
    Out = pairs; K = IDIM; KT = IDIM / 32; ntile = n * 128; expert = true;   // 52, even
  } else {
    int s = lin - 20 * 32 * NEXP;   // 0..319
    int n = s % 20;
    int m = s / 20;                 // 0..15
    mtile = m * 128;
    A = hbS; B = sd; Out = outb; K = ISDIM; KT = ISDIM / 32; ntile = n * 128; // 104, even
    expert = false;
  }

  __shared__ short Ab[2][128][32];   // 16 KB, linear
  __shared__ short Bb[2][128][32];   // 16 KB, swizzled [n][k]

  f32x4 acc[4][4];
#pragma unroll
  for (int i = 0; i < 4; ++i)
#pragma unroll
    for (int j = 0; j < 4; ++j) { f32x4 z = {0.f,0.f,0.f,0.f}; acc[i][j] = z; }

  int a_gr[2];
#pragma unroll
  for (int p = 0; p < 2; ++p) {
    int row = ((tid + (p << 8)) >> 2);
    int gr = expert ? (rowbase + mtile + row) : (mtile + row);
    if (gr > NPAIR - 1) gr = NPAIR - 1;
    a_gr[p] = gr;
  }
  const int a_ko = (tid & 3) << 3;

  const int b_n  = tid & 127;
  const int b_oh = tid >> 7;
  const float* b_base = B + ntile + b_n;

  int4  aR0[2], aR1[2];
  float bR0[16], bR1[16];

  auto loadA = [&](int kt, int4* aR) {
#pragma unroll
    for (int p = 0; p < 2; ++p)
      aR[p] = *reinterpret_cast<const int4*>(A + (size_t)a_gr[p] * K + (kt << 5) + a_ko);
  };
  auto loadB = [&](int kt, float* bR) {
    const float* p = b_base + (size_t)(kt << 5) * HDIM;
#pragma unroll
    for (int op = 0; op < 2; ++op)
#pragma unroll
      for (int j = 0; j < 8; ++j)
        bR[op * 8 + j] = p[(size_t)((b_oh * 2 + op) * 8 + j) * HDIM];
  };
  auto writeA = [&](int buf, const int4* aR) {
#pragma unroll
    for (int p = 0; p < 2; ++p)
      *reinterpret_cast<int4*>((short*)Ab[buf] + (size_t)(tid + (p << 8)) * 8) = aR[p];
  };
  auto writeB = [&](int buf, const float* bR) {
#pragma unroll
    for (int op = 0; op < 2; ++op) {
      const int oct = b_oh * 2 + op;
      const int up = oct ^ ((b_n >> 1) & 3);
      short8v s;
#pragma unroll
      for (int j = 0; j < 8; ++j) s[j] = f2bf(bR[op * 8 + j]);
      *reinterpret_cast<short8v*>(&Bb[buf][b_n][up << 3]) = s;
    }
  };

  const int lane = tid & 63;
  const int w = tid >> 6;
  const int wm = (w >> 1) * 64;
  const int wn = (w & 1) * 64;
  const int lrow = lane & 15;
  const int lkg = lane >> 4;

  auto compute = [&](int buf) {
    bf16x8 af[4], bfv[4];
#pragma unroll
    for (int mf = 0; mf < 4; ++mf)
      af[mf] = *reinterpret_cast<const bf16x8*>(&Ab[buf][wm + mf * 16 + lrow][lkg << 3]);
#pragma unroll
    for (int nf = 0; nf < 4; ++nf) {
      const int n = wn + nf * 16 + lrow;
      const int kg = (lkg ^ ((n >> 1) & 3)) << 3;
      bfv[nf] = *reinterpret_cast<const bf16x8*>(&Bb[buf][n][kg]);
    }
#pragma unroll
    for (int mf = 0; mf < 4; ++mf)
#pragma unroll
      for (int nf = 0; nf < 4; ++nf)
        acc[mf][nf] = __builtin_amdgcn_mfma_f32_16x16x32_bf16(af[mf], bfv[nf], acc[mf][nf], 0, 0, 0);
  };

  loadA(0, aR0); loadB(0, bR0);
  loadA(1, aR1); loadB(1, bR1);
  writeA(0, aR0); writeB(0, bR0);
  BAR();
  for (int kt = 0; kt < KT; kt += 2) {
    if (kt + 2 < KT) { loadA(kt + 2, aR0); loadB(kt + 2, bR0); }
    compute(0);
    writeA(1, aR1); writeB(1, bR1);
    BAR();
    if (kt + 3 < KT) { loadA(kt + 3, aR1); loadB(kt + 3, bR1); }
    compute(1);
    if (kt + 2 < KT) { writeA(0, aR0); writeB(0, bR0); }
    BAR();
  }

#pragma unroll
  for (int mf = 0; mf < 4; ++mf) {
#pragma unroll
    for (int r = 0; r < 4; ++r) {
      const int rt = wm + mf * 16 + ((lane >> 4) << 2) + r;
      const int colb = ntile + wn + lrow;
      if (expert) {
        if (mtile + rt < cnt) {
          const int gr = rowbase + mtile + rt;
          const float sc = wrow[gr];
          float* o = Out + (size_t)gr * HDIM + colb;
#pragma unroll
          for (int nf = 0; nf < 4; ++nf) o[nf * 16] = sc * acc[mf][nf][r];
        }
      } else {
        float* o = Out + (size_t)(mtile + rt) * HDIM + colb;
#pragma unroll
        for (int nf = 0; nf < 4; ++nf) o[nf * 16] = acc[mf][nf][r];
      }
    }
  }
}

// ---------------- final combine: out[t] += pairs[g0] + pairs[g1]
__global__ void combine_kernel(float* __restrict__ out, const float* __restrict__ pairs,
                               const int* __restrict__ pairpos) {
  const int t = blockIdx.x;
  const int g0 = pairpos[t * 2], g1 = pairpos[t * 2 + 1];
  const f32x4* p0 = (const f32x4*)(pairs + (size_t)g0 * HDIM);
  const f32x4* p1 = (const f32x4*)(pairs + (size_t)g1 * HDIM);
  f32x4* o = (f32x4*)(out + (size_t)t * HDIM);
  for (int c = threadIdx.x; c < HDIM / 4; c += 256)
    o[c] = o[c] + p0[c] + p1[c];
}

extern "C" void kernel_launch(void* const* d_in, const int* in_sizes, int n_in,
                              void* d_out, int out_size, void* d_ws, size_t ws_size,
                              hipStream_t stream) {
  const float* x  = (const float*)d_in[0];
  const float* rw = (const float*)d_in[1];
  const float* w1 = (const float*)d_in[2];
  const float* w3 = (const float*)d_in[3];
  const float* w2 = (const float*)d_in[4];
  const float* sg = (const float*)d_in[5];
  const float* su = (const float*)d_in[6];
  const float* sd = (const float*)d_in[7];
  float* out = (float*)d_out;
  (void)in_sizes; (void)n_in; (void)out_size; (void)ws_size;

  char* ws = (char*)d_ws;
  size_t off = 0;
  auto alloc = [&](size_t bytes) -> void* {
    void* p = ws + off;
    off = (off + bytes + 255) & ~(size_t)255;
    return p;
  };
  int*   counts  = (int*)alloc(NEXP * 4);          // @0
  int*   slotc   = (int*)alloc(NEXP * 4);          // @256
  int*   offsets = (int*)alloc(NEXP * 4);
  int*   tidx    = (int*)alloc(NPAIR * 4);
  float* tw      = (float*)alloc(NPAIR * 4);
  float* wrowv   = (float*)alloc(NPAIR * 4);
  int*   pairpos = (int*)alloc(NPAIR * 4);
  short* xb      = (short*)alloc((size_t)TOKENS * HDIM * 2);
  short* xg      = (short*)alloc((size_t)NPAIR * HDIM * 2);
  short* hbE     = (short*)alloc((size_t)NPAIR * IDIM * 2);
  short* hbS     = (short*)alloc((size_t)TOKENS * ISDIM * 2);
  float* pairs   = (float*)alloc((size_t)NPAIR * HDIM * 4);

  hipMemsetAsync(d_ws, 0, 512, stream);  // zero counts + slotc

  router_kernel<<<dim3(TOKENS), dim3(64), 0, stream>>>(x, rw, counts, tidx, tw);
  scan_kernel<<<dim3(1), dim3(64), 0, stream>>>(counts, offsets);
  gather_kernel<<<dim3(TOKENS), dim3(256), 0, stream>>>(x, tidx, tw, offsets, slotc,
                                                        pairpos, wrowv, xb, xg);

  // merged up: experts (32m x 26n x 16e = 13312) + shared (832)
  moe_up_k<<<dim3(26 * 32 * NEXP + 832), dim3(256), 0, stream>>>(
      xg, xb, w1, w3, sg, su, hbE, hbS, counts, offsets);

  // merged down: experts (32m x 20n x 16e = 10240) + shared (320)
  moe_dn_k<<<dim3(20 * 32 * NEXP + 320), dim3(256), 0, stream>>>(
      hbE, hbS, w2, sd, pairs, out, counts, offsets, wrowv);

  combine_kernel<<<dim3(TOKENS), dim3(256), 0, stream>>>(out, pairs, pairpos);
}

// Round 7
// 869.127 us; speedup vs baseline: 1.5319x; 1.5319x over previous
//
#include <hip/hip_runtime.h>
#include <hip/hip_bf16.h>

#define TOKENS 2048
#define HDIM   2560
#define NEXP   16
#define IDIM   1664
#define ISDIM  3328
#define NPAIR  (TOKENS*2)

typedef float  f32x4   __attribute__((ext_vector_type(4)));
typedef __bf16 bf16x8  __attribute__((ext_vector_type(8)));
typedef short  short8v __attribute__((ext_vector_type(8)));

#define GLDS16(g, l) __builtin_amdgcn_global_load_lds( \
    (const __attribute__((address_space(1))) unsigned int*)(g), \
    (__attribute__((address_space(3))) unsigned int*)(l), 16, 0, 0)

#define VMCNT(n) asm volatile("s_waitcnt vmcnt(" #n ")" ::: "memory")
#define LGKM_BAR() do { \
    asm volatile("s_waitcnt lgkmcnt(0)" ::: "memory"); \
    __builtin_amdgcn_sched_barrier(0); \
    __builtin_amdgcn_s_barrier(); \
    __builtin_amdgcn_sched_barrier(0); \
  } while (0)

__device__ __forceinline__ short f2bf(float f) {
  unsigned u = __builtin_bit_cast(unsigned, f);
  u += 0x7FFFu + ((u >> 16) & 1u);          // RNE to bf16
  return (short)(u >> 16);
}

// ---------------- router: fp32 logits, softmax-top2-renorm == sigmoid(l0-l1)
__global__ void router_kernel(const float* __restrict__ x, const float* __restrict__ rw,
                              int* __restrict__ counts, int* __restrict__ tidx,
                              float* __restrict__ tw) {
  const int t = blockIdx.x;
  const int lane = threadIdx.x;
  float acc[NEXP];
#pragma unroll
  for (int e = 0; e < NEXP; ++e) acc[e] = 0.f;
  const float* xr = x + (size_t)t * HDIM;
  for (int k = lane; k < HDIM; k += 64) {
    float xv = xr[k];
#pragma unroll
    for (int e = 0; e < NEXP; ++e) acc[e] += xv * rw[e * HDIM + k];
  }
#pragma unroll
  for (int e = 0; e < NEXP; ++e) {
#pragma unroll
    for (int o = 32; o > 0; o >>= 1) acc[e] += __shfl_down(acc[e], o);
  }
  if (lane == 0) {
    int i0 = 0; float v0 = acc[0];
#pragma unroll
    for (int e = 1; e < NEXP; ++e) if (acc[e] > v0) { v0 = acc[e]; i0 = e; }
    int i1 = -1; float v1 = -3.4e38f;
#pragma unroll
    for (int e = 0; e < NEXP; ++e) if (e != i0 && acc[e] > v1) { v1 = acc[e]; i1 = e; }
    float w0 = 1.f / (1.f + expf(v1 - v0));
    tidx[t * 2] = i0; tidx[t * 2 + 1] = i1;
    tw[t * 2] = w0;   tw[t * 2 + 1] = 1.f - w0;
    atomicAdd(&counts[i0], 1);
    atomicAdd(&counts[i1], 1);
  }
}

__global__ void scan_kernel(const int* __restrict__ counts, int* __restrict__ offsets) {
  if (threadIdx.x == 0) {
    int a = 0;
    for (int e = 0; e < NEXP; ++e) { offsets[e] = a; a += counts[e]; }
  }
}

// ---------------- bucket pairs + gather bf16 activations
__global__ void gather_kernel(const float* __restrict__ x, const int* __restrict__ tidx,
                              const float* __restrict__ tw, const int* __restrict__ offsets,
                              int* __restrict__ slotc, int* __restrict__ pairpos,
                              float* __restrict__ wrow, short* __restrict__ xb,
                              short* __restrict__ xg) {
  const int t = blockIdx.x, tid = threadIdx.x;
  __shared__ int grs[2];
  if (tid < 2) {
    int e = tidx[t * 2 + tid];
    int slot = atomicAdd(&slotc[e], 1);
    int g = offsets[e] + slot;
    grs[tid] = g;
    pairpos[t * 2 + tid] = g;
    wrow[g] = tw[t * 2 + tid];
  }
  __syncthreads();
  const int g0 = grs[0], g1 = grs[1];
  const float* xr = x + (size_t)t * HDIM;
#pragma unroll
  for (int i = 0; i < HDIM / 256; ++i) {
    int k = tid + i * 256;
    short v = f2bf(xr[k]);
    xb[(size_t)t * HDIM + k] = v;
    xg[(size_t)g0 * HDIM + k] = v;
    xg[(size_t)g1 * HDIM + k] = v;
  }
}

// ================= merged UP: H = bf16( silu(A*B1) * (A*B3) )
// BM=128, BN=64, BK=32, 256 thr, 4 waves in M, wave tile 32x64.
// A: global_load_lds double-buffer. B: depth-2 pipeline in NAMED f32x4 regs
// (tile k+2 loading while k+1 ds-writes and k computes). Counted vmcnt(16) at
// the barrier keeps the 16 B loads in flight; only the 2 A-glds drain.
__launch_bounds__(256, 2)
__global__ void moe_up_k(const short* __restrict__ xg, const short* __restrict__ xb,
                         const float* __restrict__ w1, const float* __restrict__ w3,
                         const float* __restrict__ sg, const float* __restrict__ su,
                         short* __restrict__ hbE, short* __restrict__ hbS,
                         const int* __restrict__ counts, const int* __restrict__ offsets) {
  const int tid = threadIdx.x;
  const int lin = blockIdx.x;
  const short* A; const float* B1; const float* B3; short* H;
  int N, mtile, ntile, rowbase = 0, cnt = 0x7fffffff;
  bool expert;
  if (lin < 26 * 32 * NEXP) {
    // 13312 = 8 XCD x 1664; m fastest -> m-siblings of an (e,n) adjacent (L2)
    int idx = (lin & 7) * 1664 + (lin >> 3);
    int m = idx & 31;
    int rest = idx >> 5;          // 0..415
    int n = rest % 26;
    int e = rest / 26;
    cnt = counts[e];
    mtile = m * 128;
    if (mtile >= cnt) return;
    rowbase = offsets[e];
    A = xg; B1 = w1 + (size_t)e * HDIM * IDIM; B3 = w3 + (size_t)e * HDIM * IDIM;
    H = hbE; N = IDIM; ntile = n * 64; expert = true;
  } else {
    int s = lin - 26 * 32 * NEXP;   // 0..831
    int n = s % 52;
    int m = s / 52;                 // 0..15
    mtile = m * 128;
    A = xb; B1 = sg; B3 = su; H = hbS; N = ISDIM; ntile = n * 64; expert = false;
  }
  const int K = HDIM;
  const int KT = HDIM / 32;         // 80, even

  __shared__ short Ab[2][128][32];       // 8 KB x2, linear
  __shared__ short Bb[2][2][64][32];     // swizzled [n][k]

  f32x4 accG[2][4], accU[2][4];
#pragma unroll
  for (int i = 0; i < 2; ++i)
#pragma unroll
    for (int j = 0; j < 4; ++j) { f32x4 z = {0.f,0.f,0.f,0.f}; accG[i][j] = z; accU[i][j] = z; }

  // A staging (GLDS): pass p covers rows p*64 + tid/4, unit tid&3
  int gr0, gr1;
  {
    int r0 = tid >> 2, r1 = (tid >> 2) + 64;
    gr0 = expert ? (rowbase + mtile + r0) : (mtile + r0);
    gr1 = expert ? (rowbase + mtile + r1) : (mtile + r1);
    if (gr0 > NPAIR - 1) gr0 = NPAIR - 1;
    if (gr1 > NPAIR - 1) gr1 = NPAIR - 1;
  }
  const int a_ko = (tid & 3) << 3;
  const short* a_src0 = A + (size_t)gr0 * K + a_ko;
  const short* a_src1 = A + (size_t)gr1 * K + a_ko;

#define STAGEA_U(kt, buf) do { \
    GLDS16(a_src0 + ((kt) << 5), (short*)Ab[buf] + tid * 8); \
    GLDS16(a_src1 + ((kt) << 5), (short*)Ab[buf] + (tid + 256) * 8); \
  } while (0)

  // B staging: matrix sm = tid>>7, col n = tid&63, row-half b_oh
  const int b_sm = tid >> 7;
  const int b_n  = tid & 63;
  const int b_oh = (tid >> 6) & 1;
  const float* b_base = (b_sm ? B3 : B1) + ntile + b_n;
  const int u0s = (b_oh * 2) ^ ((b_n >> 1) & 3);
  const int u1s = (b_oh * 2 + 1) ^ ((b_n >> 1) & 3);

  f32x4 s0a, s0b, s0c, s0d, s1a, s1b, s1c, s1d;

#define LOADB_U(kt, va, vb, vc, vd) do { \
    const float* p_ = b_base + (size_t)((kt) * 32 + b_oh * 16) * N; \
    va[0] = p_[0];               va[1] = p_[(size_t)1 * N]; \
    va[2] = p_[(size_t)2 * N];   va[3] = p_[(size_t)3 * N]; \
    vb[0] = p_[(size_t)4 * N];   vb[1] = p_[(size_t)5 * N]; \
    vb[2] = p_[(size_t)6 * N];   vb[3] = p_[(size_t)7 * N]; \
    vc[0] = p_[(size_t)8 * N];   vc[1] = p_[(size_t)9 * N]; \
    vc[2] = p_[(size_t)10 * N];  vc[3] = p_[(size_t)11 * N]; \
    vd[0] = p_[(size_t)12 * N];  vd[1] = p_[(size_t)13 * N]; \
    vd[2] = p_[(size_t)14 * N];  vd[3] = p_[(size_t)15 * N]; \
  } while (0)

#define WRITEB_U(buf, va, vb, vc, vd) do { \
    short8v t0_, t1_; \
    t0_[0]=f2bf(va[0]); t0_[1]=f2bf(va[1]); t0_[2]=f2bf(va[2]); t0_[3]=f2bf(va[3]); \
    t0_[4]=f2bf(vb[0]); t0_[5]=f2bf(vb[1]); t0_[6]=f2bf(vb[2]); t0_[7]=f2bf(vb[3]); \
    t1_[0]=f2bf(vc[0]); t1_[1]=f2bf(vc[1]); t1_[2]=f2bf(vc[2]); t1_[3]=f2bf(vc[3]); \
    t1_[4]=f2bf(vd[0]); t1_[5]=f2bf(vd[1]); t1_[6]=f2bf(vd[2]); t1_[7]=f2bf(vd[3]); \
    *reinterpret_cast<short8v*>(&Bb[buf][b_sm][b_n][u0s << 3]) = t0_; \
    *reinterpret_cast<short8v*>(&Bb[buf][b_sm][b_n][u1s << 3]) = t1_; \
  } while (0)

  const int lane = tid & 63;
  const int w = tid >> 6;
  const int wm = w * 32;
  const int lrow = lane & 15;
  const int lkg = lane >> 4;

  auto compute = [&](int buf) {
    bf16x8 af[2], bG[4], bU[4];
#pragma unroll
    for (int mf = 0; mf < 2; ++mf)
      af[mf] = *reinterpret_cast<const bf16x8*>(&Ab[buf][wm + mf * 16 + lrow][lkg << 3]);
#pragma unroll
    for (int nf = 0; nf < 4; ++nf) {
      const int n = nf * 16 + lrow;
      const int kg = (lkg ^ ((n >> 1) & 3)) << 3;
      bG[nf] = *reinterpret_cast<const bf16x8*>(&Bb[buf][0][n][kg]);
      bU[nf] = *reinterpret_cast<const bf16x8*>(&Bb[buf][1][n][kg]);
    }
#pragma unroll
    for (int mf = 0; mf < 2; ++mf)
#pragma unroll
      for (int nf = 0; nf < 4; ++nf) {
        accG[mf][nf] = __builtin_amdgcn_mfma_f32_16x16x32_bf16(af[mf], bG[nf], accG[mf][nf], 0, 0, 0);
        accU[mf][nf] = __builtin_amdgcn_mfma_f32_16x16x32_bf16(af[mf], bU[nf], accU[mf][nf], 0, 0, 0);
      }
  };

  // prologue: Ab[0]=A(0); Bb[0]=B(0); S1=B(1) in flight
  STAGEA_U(0, 0);
  LOADB_U(0, s0a, s0b, s0c, s0d);
  LOADB_U(1, s1a, s1b, s1c, s1d);
  WRITEB_U(0, s0a, s0b, s0c, s0d);   // waits S0; A glds are older -> also done
  VMCNT(16);
  LGKM_BAR();

  for (int kt = 0; kt < KT; kt += 2) {
    // even: compute tile kt (buf0); A(kt+1)->Ab[1]; B(kt+1)->Bb[1]; load B(kt+2)->S0
    if (kt + 1 < KT) { STAGEA_U(kt + 1, 1); WRITEB_U(1, s1a, s1b, s1c, s1d); }
    if (kt + 2 < KT) LOADB_U(kt + 2, s0a, s0b, s0c, s0d);
    compute(0);
    if (kt + 2 < KT) { VMCNT(16); } else { VMCNT(0); }
    LGKM_BAR();
    // odd: compute tile kt+1 (buf1); A(kt+2)->Ab[0]; B(kt+2)->Bb[0]; load B(kt+3)->S1
    if (kt + 2 < KT) { STAGEA_U(kt + 2, 0); WRITEB_U(0, s0a, s0b, s0c, s0d); }
    if (kt + 3 < KT) LOADB_U(kt + 3, s1a, s1b, s1c, s1d);
    compute(1);
    if (kt + 3 < KT) { VMCNT(16); } else { VMCNT(0); }
    LGKM_BAR();
  }

  // epilogue: silu(g)*u -> bf16. C/D: col=lane&15, row=(lane>>4)*4+r
#pragma unroll
  for (int mf = 0; mf < 2; ++mf) {
#pragma unroll
    for (int r = 0; r < 4; ++r) {
      const int rt = wm + mf * 16 + ((lane >> 4) << 2) + r;
      if (expert && mtile + rt >= cnt) continue;
      const size_t grow = (size_t)((expert ? rowbase : 0) + mtile + rt);
      const int colb = ntile + lrow;
#pragma unroll
      for (int nf = 0; nf < 4; ++nf) {
        float g = accG[mf][nf][r];
        float u = accU[mf][nf][r];
        H[grow * N + colb + nf * 16] = f2bf(g / (1.f + expf(-g)) * u);
      }
    }
  }
#undef STAGEA_U
#undef LOADB_U
#undef WRITEB_U
}

// ================= merged DOWN: Out = A*B.  BM=128, BN=128, BK=32, 256 thr,
// 4 waves (2M x 2N), wave tile 64x64.  Same depth-2 named-register pipeline.
__launch_bounds__(256, 2)
__global__ void moe_dn_k(const short* __restrict__ hbE, const short* __restrict__ hbS,
                         const float* __restrict__ w2, const float* __restrict__ sd,
                         float* __restrict__ pairs, float* __restrict__ outb,
                         const int* __restrict__ counts, const int* __restrict__ offsets,
                         const float* __restrict__ wrow) {
  const int tid = threadIdx.x;
  const int lin = blockIdx.x;
  const short* A; const float* B; float* Out;
  int K, KT, mtile, ntile, rowbase = 0, cnt = 0x7fffffff;
  bool expert;
  if (lin < 20 * 32 * NEXP) {
    // 10240 = 8 XCD x 1280; m fastest
    int idx = (lin & 7) * 1280 + (lin >> 3);
    int m = idx & 31;
    int rest = idx >> 5;          // 0..319
    int n = rest % 20;
    int e = rest / 20;
    cnt = counts[e];
    mtile = m * 128;
    if (mtile >= cnt) return;
    rowbase = offsets[e];
    A = hbE; B = w2 + (size_t)e * IDIM * HDIM;
    Out = pairs; K = IDIM; KT = IDIM / 32; ntile = n * 128; expert = true;   // KT=52
  } else {
    int s = lin - 20 * 32 * NEXP;   // 0..319
    int n = s % 20;
    int m = s / 20;                 // 0..15
    mtile = m * 128;
    A = hbS; B = sd; Out = outb; K = ISDIM; KT = ISDIM / 32; ntile = n * 128; // KT=104
    expert = false;
  }

  __shared__ short Ab[2][128][32];   // linear
  __shared__ short Bb[2][128][32];   // swizzled [n][k]

  f32x4 acc[4][4];
#pragma unroll
  for (int i = 0; i < 4; ++i)
#pragma unroll
    for (int j = 0; j < 4; ++j) { f32x4 z = {0.f,0.f,0.f,0.f}; acc[i][j] = z; }

  int gr0, gr1;
  {
    int r0 = tid >> 2, r1 = (tid >> 2) + 64;
    gr0 = expert ? (rowbase + mtile + r0) : (mtile + r0);
    gr1 = expert ? (rowbase + mtile + r1) : (mtile + r1);
    if (gr0 > NPAIR - 1) gr0 = NPAIR - 1;
    if (gr1 > NPAIR - 1) gr1 = NPAIR - 1;
  }
  const int a_ko = (tid & 3) << 3;
  const short* a_src0 = A + (size_t)gr0 * K + a_ko;
  const short* a_src1 = A + (size_t)gr1 * K + a_ko;

#define STAGEA_D(kt, buf) do { \
    GLDS16(a_src0 + ((kt) << 5), (short*)Ab[buf] + tid * 8); \
    GLDS16(a_src1 + ((kt) << 5), (short*)Ab[buf] + (tid + 256) * 8); \
  } while (0)

  const int b_n  = tid & 127;
  const int b_oh = tid >> 7;
  const float* b_base = B + ntile + b_n;
  const int u0s = (b_oh * 2) ^ ((b_n >> 1) & 3);
  const int u1s = (b_oh * 2 + 1) ^ ((b_n >> 1) & 3);

  f32x4 s0a, s0b, s0c, s0d, s1a, s1b, s1c, s1d;

#define LOADB_D(kt, va, vb, vc, vd) do { \
    const float* p_ = b_base + (size_t)((kt) * 32 + b_oh * 16) * HDIM; \
    va[0] = p_[0];                  va[1] = p_[(size_t)1 * HDIM]; \
    va[2] = p_[(size_t)2 * HDIM];   va[3] = p_[(size_t)3 * HDIM]; \
    vb[0] = p_[(size_t)4 * HDIM];   vb[1] = p_[(size_t)5 * HDIM]; \
    vb[2] = p_[(size_t)6 * HDIM];   vb[3] = p_[(size_t)7 * HDIM]; \
    vc[0] = p_[(size_t)8 * HDIM];   vc[1] = p_[(size_t)9 * HDIM]; \
    vc[2] = p_[(size_t)10 * HDIM];  vc[3] = p_[(size_t)11 * HDIM]; \
    vd[0] = p_[(size_t)12 * HDIM];  vd[1] = p_[(size_t)13 * HDIM]; \
    vd[2] = p_[(size_t)14 * HDIM];  vd[3] = p_[(size_t)15 * HDIM]; \
  } while (0)

#define WRITEB_D(buf, va, vb, vc, vd) do { \
    short8v t0_, t1_; \
    t0_[0]=f2bf(va[0]); t0_[1]=f2bf(va[1]); t0_[2]=f2bf(va[2]); t0_[3]=f2bf(va[3]); \
    t0_[4]=f2bf(vb[0]); t0_[5]=f2bf(vb[1]); t0_[6]=f2bf(vb[2]); t0_[7]=f2bf(vb[3]); \
    t1_[0]=f2bf(vc[0]); t1_[1]=f2bf(vc[1]); t1_[2]=f2bf(vc[2]); t1_[3]=f2bf(vc[3]); \
    t1_[4]=f2bf(vd[0]); t1_[5]=f2bf(vd[1]); t1_[6]=f2bf(vd[2]); t1_[7]=f2bf(vd[3]); \
    *reinterpret_cast<short8v*>(&Bb[buf][b_n][u0s << 3]) = t0_; \
    *reinterpret_cast<short8v*>(&Bb[buf][b_n][u1s << 3]) = t1_; \
  } while (0)

  const int lane = tid & 63;
  const int w = tid >> 6;
  const int wm = (w >> 1) * 64;
  const int wn = (w & 1) * 64;
  const int lrow = lane & 15;
  const int lkg = lane >> 4;

  auto compute = [&](int buf) {
    bf16x8 af[4], bfv[4];
#pragma unroll
    for (int mf = 0; mf < 4; ++mf)
      af[mf] = *reinterpret_cast<const bf16x8*>(&Ab[buf][wm + mf * 16 + lrow][lkg << 3]);
#pragma unroll
    for (int nf = 0; nf < 4; ++nf) {
      const int n = wn + nf * 16 + lrow;
      const int kg = (lkg ^ ((n >> 1) & 3)) << 3;
      bfv[nf] = *reinterpret_cast<const bf16x8*>(&Bb[buf][n][kg]);
    }
#pragma unroll
    for (int mf = 0; mf < 4; ++mf)
#pragma unroll
      for (int nf = 0; nf < 4; ++nf)
        acc[mf][nf] = __builtin_amdgcn_mfma_f32_16x16x32_bf16(af[mf], bfv[nf], acc[mf][nf], 0, 0, 0);
  };

  STAGEA_D(0, 0);
  LOADB_D(0, s0a, s0b, s0c, s0d);
  LOADB_D(1, s1a, s1b, s1c, s1d);
  WRITEB_D(0, s0a, s0b, s0c, s0d);
  VMCNT(16);
  LGKM_BAR();

  for (int kt = 0; kt < KT; kt += 2) {
    if (kt + 1 < KT) { STAGEA_D(kt + 1, 1); WRITEB_D(1, s1a, s1b, s1c, s1d); }
    if (kt + 2 < KT) LOADB_D(kt + 2, s0a, s0b, s0c, s0d);
    compute(0);
    if (kt + 2 < KT) { VMCNT(16); } else { VMCNT(0); }
    LGKM_BAR();
    if (kt + 2 < KT) { STAGEA_D(kt + 2, 0); WRITEB_D(0, s0a, s0b, s0c, s0d); }
    if (kt + 3 < KT) LOADB_D(kt + 3, s1a, s1b, s1c, s1d);
    compute(1);
    if (kt + 3 < KT) { VMCNT(16); } else { VMCNT(0); }
    LGKM_BAR();
  }

#pragma unroll
  for (int mf = 0; mf < 4; ++mf) {
#pragma unroll
    for (int r = 0; r < 4; ++r) {
      const int rt = wm + mf * 16 + ((lane >> 4) << 2) + r;
      const int colb = ntile + wn + lrow;
      if (expert) {
        if (mtile + rt < cnt) {
          const int gr = rowbase + mtile + rt;
          const float sc = wrow[gr];
          float* o = Out + (size_t)gr * HDIM + colb;
#pragma unroll
          for (int nf = 0; nf < 4; ++nf) o[nf * 16] = sc * acc[mf][nf][r];
        }
      } else {
        float* o = Out + (size_t)(mtile + rt) * HDIM + colb;
#pragma unroll
        for (int nf = 0; nf < 4; ++nf) o[nf * 16] = acc[mf][nf][r];
      }
    }
  }
#undef STAGEA_D
#undef LOADB_D
#undef WRITEB_D
}

// ---------------- final combine: out[t] += pairs[g0] + pairs[g1]
__global__ void combine_kernel(float* __restrict__ out, const float* __restrict__ pairs,
                               const int* __restrict__ pairpos) {
  const int t = blockIdx.x;
  const int g0 = pairpos[t * 2], g1 = pairpos[t * 2 + 1];
  const f32x4* p0 = (const f32x4*)(pairs + (size_t)g0 * HDIM);
  const f32x4* p1 = (const f32x4*)(pairs + (size_t)g1 * HDIM);
  f32x4* o = (f32x4*)(out + (size_t)t * HDIM);
  for (int c = threadIdx.x; c < HDIM / 4; c += 256)
    o[c] = o[c] + p0[c] + p1[c];
}

extern "C" void kernel_launch(void* const* d_in, const int* in_sizes, int n_in,
                              void* d_out, int out_size, void* d_ws, size_t ws_size,
                              hipStream_t stream) {
  const float* x  = (const float*)d_in[0];
  const float* rw = (const float*)d_in[1];
  const float* w1 = (const float*)d_in[2];
  const float* w3 = (const float*)d_in[3];
  const float* w2 = (const float*)d_in[4];
  const float* sg = (const float*)d_in[5];
  const float* su = (const float*)d_in[6];
  const float* sd = (const float*)d_in[7];
  float* out = (float*)d_out;
  (void)in_sizes; (void)n_in; (void)out_size; (void)ws_size;

  char* ws = (char*)d_ws;
  size_t off = 0;
  auto alloc = [&](size_t bytes) -> void* {
    void* p = ws + off;
    off = (off + bytes + 255) & ~(size_t)255;
    return p;
  };
  int*   counts  = (int*)alloc(NEXP * 4);          // @0
  int*   slotc   = (int*)alloc(NEXP * 4);          // @256
  int*   offsets = (int*)alloc(NEXP * 4);
  int*   tidx    = (int*)alloc(NPAIR * 4);
  float* tw      = (float*)alloc(NPAIR * 4);
  float* wrowv   = (float*)alloc(NPAIR * 4);
  int*   pairpos = (int*)alloc(NPAIR * 4);
  short* xb      = (short*)alloc((size_t)TOKENS * HDIM * 2);
  short* xg      = (short*)alloc((size_t)NPAIR * HDIM * 2);
  short* hbE     = (short*)alloc((size_t)NPAIR * IDIM * 2);
  short* hbS     = (short*)alloc((size_t)TOKENS * ISDIM * 2);
  float* pairs   = (float*)alloc((size_t)NPAIR * HDIM * 4);

  hipMemsetAsync(d_ws, 0, 512, stream);  // zero counts + slotc

  router_kernel<<<dim3(TOKENS), dim3(64), 0, stream>>>(x, rw, counts, tidx, tw);
  scan_kernel<<<dim3(1), dim3(64), 0, stream>>>(counts, offsets);
  gather_kernel<<<dim3(TOKENS), dim3(256), 0, stream>>>(x, tidx, tw, offsets, slotc,
                                                        pairpos, wrowv, xb, xg);

  // merged up: experts (32m x 26n x 16e = 13312) + shared (832)
  moe_up_k<<<dim3(26 * 32 * NEXP + 832), dim3(256), 0, stream>>>(
      xg, xb, w1, w3, sg, su, hbE, hbS, counts, offsets);

  // merged down: experts (32m x 20n x 16e = 10240) + shared (320)
  moe_dn_k<<<dim3(20 * 32 * NEXP + 320), dim3(256), 0, stream>>>(
      hbE, hbS, w2, sd, pairs, out, counts, offsets, wrowv);

  combine_kernel<<<dim3(TOKENS), dim3(256), 0, stream>>>(out, pairs, pairpos);
}

// Round 8
// 820.320 us; speedup vs baseline: 1.6231x; 1.0595x over previous
//
#include <hip/hip_runtime.h>
#include <hip/hip_bf16.h>

#define TOKENS 2048
#define HDIM   2560
#define NEXP   16
#define IDIM   1664
#define ISDIM  3328
#define NPAIR  (TOKENS*2)

typedef float  f32x4   __attribute__((ext_vector_type(4)));
typedef __bf16 bf16x8  __attribute__((ext_vector_type(8)));
typedef short  short8v __attribute__((ext_vector_type(8)));

#define GLDS16(g, l) __builtin_amdgcn_global_load_lds( \
    (const __attribute__((address_space(1))) unsigned int*)(g), \
    (__attribute__((address_space(3))) unsigned int*)(l), 16, 0, 0)

#define VMCNT(n) asm volatile("s_waitcnt vmcnt(" #n ")" ::: "memory")
#define LGKM_BAR() do { \
    asm volatile("s_waitcnt lgkmcnt(0)" ::: "memory"); \
    __builtin_amdgcn_sched_barrier(0); \
    __builtin_amdgcn_s_barrier(); \
    __builtin_amdgcn_sched_barrier(0); \
  } while (0)

__device__ __forceinline__ short f2bf(float f) {
  unsigned u = __builtin_bit_cast(unsigned, f);
  u += 0x7FFFu + ((u >> 16) & 1u);          // RNE to bf16
  return (short)(u >> 16);
}

// ---------------- router: fp32 logits, softmax-top2-renorm == sigmoid(l0-l1)
__global__ void router_kernel(const float* __restrict__ x, const float* __restrict__ rw,
                              int* __restrict__ counts, int* __restrict__ tidx,
                              float* __restrict__ tw) {
  const int t = blockIdx.x;
  const int lane = threadIdx.x;
  float acc[NEXP];
#pragma unroll
  for (int e = 0; e < NEXP; ++e) acc[e] = 0.f;
  const float* xr = x + (size_t)t * HDIM;
  for (int k = lane; k < HDIM; k += 64) {
    float xv = xr[k];
#pragma unroll
    for (int e = 0; e < NEXP; ++e) acc[e] += xv * rw[e * HDIM + k];
  }
#pragma unroll
  for (int e = 0; e < NEXP; ++e) {
#pragma unroll
    for (int o = 32; o > 0; o >>= 1) acc[e] += __shfl_down(acc[e], o);
  }
  if (lane == 0) {
    int i0 = 0; float v0 = acc[0];
#pragma unroll
    for (int e = 1; e < NEXP; ++e) if (acc[e] > v0) { v0 = acc[e]; i0 = e; }
    int i1 = -1; float v1 = -3.4e38f;
#pragma unroll
    for (int e = 0; e < NEXP; ++e) if (e != i0 && acc[e] > v1) { v1 = acc[e]; i1 = e; }
    float w0 = 1.f / (1.f + expf(v1 - v0));
    tidx[t * 2] = i0; tidx[t * 2 + 1] = i1;
    tw[t * 2] = w0;   tw[t * 2 + 1] = 1.f - w0;
    atomicAdd(&counts[i0], 1);
    atomicAdd(&counts[i1], 1);
  }
}

__global__ void scan_kernel(const int* __restrict__ counts, int* __restrict__ offsets) {
  if (threadIdx.x == 0) {
    int a = 0;
    for (int e = 0; e < NEXP; ++e) { offsets[e] = a; a += counts[e]; }
  }
}

// ---------------- bucket pairs + gather bf16 activations
__global__ void gather_kernel(const float* __restrict__ x, const int* __restrict__ tidx,
                              const float* __restrict__ tw, const int* __restrict__ offsets,
                              int* __restrict__ slotc, int* __restrict__ pairpos,
                              float* __restrict__ wrow, short* __restrict__ xb,
                              short* __restrict__ xg) {
  const int t = blockIdx.x, tid = threadIdx.x;
  __shared__ int grs[2];
  if (tid < 2) {
    int e = tidx[t * 2 + tid];
    int slot = atomicAdd(&slotc[e], 1);
    int g = offsets[e] + slot;
    grs[tid] = g;
    pairpos[t * 2 + tid] = g;
    wrow[g] = tw[t * 2 + tid];
  }
  __syncthreads();
  const int g0 = grs[0], g1 = grs[1];
  const float* xr = x + (size_t)t * HDIM;
#pragma unroll
  for (int i = 0; i < HDIM / 256; ++i) {
    int k = tid + i * 256;
    short v = f2bf(xr[k]);
    xb[(size_t)t * HDIM + k] = v;
    xg[(size_t)g0 * HDIM + k] = v;
    xg[(size_t)g1 * HDIM + k] = v;
  }
}

// ================= merged UP: H = bf16( silu(A*B1) * (A*B3) )
// BM=128, BN=64(dual), BK=32, 256 thr.  Depth-4 pipeline:
// step s issues {STAGEA(s+3) 2 glds, LOADB(s+4) 16 loads}; VMCNT(36) at the
// barrier drains everything older than the last 2 steps -> 2-step latency
// budget for both A and B, count robust to intra-step reordering.
__launch_bounds__(256, 2)
__global__ void moe_up_k(const short* __restrict__ xg, const short* __restrict__ xb,
                         const float* __restrict__ w1, const float* __restrict__ w3,
                         const float* __restrict__ sg, const float* __restrict__ su,
                         short* __restrict__ hbE, short* __restrict__ hbS,
                         const int* __restrict__ counts, const int* __restrict__ offsets) {
  const int tid = threadIdx.x;
  const int lin = blockIdx.x;
  const short* A; const float* B1; const float* B3; short* H;
  int N, mtile, ntile, rowbase = 0, cnt = 0x7fffffff;
  bool expert;
  if (lin < 26 * 32 * NEXP) {
    int idx = (lin & 7) * 1664 + (lin >> 3);
    int m = idx & 31;
    int rest = idx >> 5;
    int n = rest % 26;
    int e = rest / 26;
    cnt = counts[e];
    mtile = m * 128;
    if (mtile >= cnt) return;
    rowbase = offsets[e];
    A = xg; B1 = w1 + (size_t)e * HDIM * IDIM; B3 = w3 + (size_t)e * HDIM * IDIM;
    H = hbE; N = IDIM; ntile = n * 64; expert = true;
  } else {
    int s = lin - 26 * 32 * NEXP;
    int n = s % 52;
    int m = s / 52;
    mtile = m * 128;
    A = xb; B1 = sg; B3 = su; H = hbS; N = ISDIM; ntile = n * 64; expert = false;
  }
  const int K = HDIM;
  const int KT = HDIM / 32;         // 80 (div by 4; KT-4 div by 4)

  __shared__ short Ab[4][128][32];       // 32 KB, linear, 4-deep
  __shared__ short Bb[2][2][64][32];     // 16 KB, swizzled [n][k]

  f32x4 accG[2][4], accU[2][4];
#pragma unroll
  for (int i = 0; i < 2; ++i)
#pragma unroll
    for (int j = 0; j < 4; ++j) { f32x4 z = {0.f,0.f,0.f,0.f}; accG[i][j] = z; accU[i][j] = z; }

  int gr0, gr1;
  {
    int r0 = tid >> 2, r1 = (tid >> 2) + 64;
    gr0 = expert ? (rowbase + mtile + r0) : (mtile + r0);
    gr1 = expert ? (rowbase + mtile + r1) : (mtile + r1);
    if (gr0 > NPAIR - 1) gr0 = NPAIR - 1;
    if (gr1 > NPAIR - 1) gr1 = NPAIR - 1;
  }
  const int a_ko = (tid & 3) << 3;
  const short* a_src0 = A + (size_t)gr0 * K + a_ko;
  const short* a_src1 = A + (size_t)gr1 * K + a_ko;

#define STAGEA_U(kt, buf) do { \
    GLDS16(a_src0 + ((kt) << 5), (short*)Ab[buf] + tid * 8); \
    GLDS16(a_src1 + ((kt) << 5), (short*)Ab[buf] + (tid + 256) * 8); \
  } while (0)

  const int b_sm = tid >> 7;
  const int b_n  = tid & 63;
  const int b_oh = (tid >> 6) & 1;
  const float* b_base = (b_sm ? B3 : B1) + ntile + b_n;
  const int u0s = (b_oh * 2) ^ ((b_n >> 1) & 3);
  const int u1s = (b_oh * 2 + 1) ^ ((b_n >> 1) & 3);

  f32x4 T0a,T0b,T0c,T0d, T1a,T1b,T1c,T1d, T2a,T2b,T2c,T2d, T3a,T3b,T3c,T3d;

#define LOADB_U(kt, va, vb, vc, vd) do { \
    const float* p_ = b_base + (size_t)((kt) * 32 + b_oh * 16) * N; \
    va[0] = p_[0];               va[1] = p_[(size_t)1 * N]; \
    va[2] = p_[(size_t)2 * N];   va[3] = p_[(size_t)3 * N]; \
    vb[0] = p_[(size_t)4 * N];   vb[1] = p_[(size_t)5 * N]; \
    vb[2] = p_[(size_t)6 * N];   vb[3] = p_[(size_t)7 * N]; \
    vc[0] = p_[(size_t)8 * N];   vc[1] = p_[(size_t)9 * N]; \
    vc[2] = p_[(size_t)10 * N];  vc[3] = p_[(size_t)11 * N]; \
    vd[0] = p_[(size_t)12 * N];  vd[1] = p_[(size_t)13 * N]; \
    vd[2] = p_[(size_t)14 * N];  vd[3] = p_[(size_t)15 * N]; \
  } while (0)

#define WRITEB_U(buf, va, vb, vc, vd) do { \
    short8v t0_, t1_; \
    t0_[0]=f2bf(va[0]); t0_[1]=f2bf(va[1]); t0_[2]=f2bf(va[2]); t0_[3]=f2bf(va[3]); \
    t0_[4]=f2bf(vb[0]); t0_[5]=f2bf(vb[1]); t0_[6]=f2bf(vb[2]); t0_[7]=f2bf(vb[3]); \
    t1_[0]=f2bf(vc[0]); t1_[1]=f2bf(vc[1]); t1_[2]=f2bf(vc[2]); t1_[3]=f2bf(vc[3]); \
    t1_[4]=f2bf(vd[0]); t1_[5]=f2bf(vd[1]); t1_[6]=f2bf(vd[2]); t1_[7]=f2bf(vd[3]); \
    *reinterpret_cast<short8v*>(&Bb[buf][b_sm][b_n][u0s << 3]) = t0_; \
    *reinterpret_cast<short8v*>(&Bb[buf][b_sm][b_n][u1s << 3]) = t1_; \
  } while (0)

  const int lane = tid & 63;
  const int w = tid >> 6;
  const int wm = w * 32;
  const int lrow = lane & 15;
  const int lkg = lane >> 4;

  auto compute = [&](int ab, int bb) {
    bf16x8 af[2], bG[4], bU[4];
#pragma unroll
    for (int mf = 0; mf < 2; ++mf)
      af[mf] = *reinterpret_cast<const bf16x8*>(&Ab[ab][wm + mf * 16 + lrow][lkg << 3]);
#pragma unroll
    for (int nf = 0; nf < 4; ++nf) {
      const int n = nf * 16 + lrow;
      const int kg = (lkg ^ ((n >> 1) & 3)) << 3;
      bG[nf] = *reinterpret_cast<const bf16x8*>(&Bb[bb][0][n][kg]);
      bU[nf] = *reinterpret_cast<const bf16x8*>(&Bb[bb][1][n][kg]);
    }
#pragma unroll
    for (int mf = 0; mf < 2; ++mf)
#pragma unroll
      for (int nf = 0; nf < 4; ++nf) {
        accG[mf][nf] = __builtin_amdgcn_mfma_f32_16x16x32_bf16(af[mf], bG[nf], accG[mf][nf], 0, 0, 0);
        accU[mf][nf] = __builtin_amdgcn_mfma_f32_16x16x32_bf16(af[mf], bU[nf], accU[mf][nf], 0, 0, 0);
      }
  };

  // prologue: A(0..2) staged, B(0..3) in regs, Bb[0] <- B(0)
  STAGEA_U(0, 0); STAGEA_U(1, 1); STAGEA_U(2, 2);
  LOADB_U(0, T0a,T0b,T0c,T0d);
  LOADB_U(1, T1a,T1b,T1c,T1d);
  LOADB_U(2, T2a,T2b,T2c,T2d);
  LOADB_U(3, T3a,T3b,T3c,T3d);
  WRITEB_U(0, T0a,T0b,T0c,T0d);
  VMCNT(0);
  LGKM_BAR();

  int kt = 0;
  for (; kt < KT - 4; kt += 4) {
    STAGEA_U(kt + 3, 3); WRITEB_U(1, T1a,T1b,T1c,T1d); LOADB_U(kt + 4, T0a,T0b,T0c,T0d);
    compute(0, 0); VMCNT(36); LGKM_BAR();
    STAGEA_U(kt + 4, 0); WRITEB_U(0, T2a,T2b,T2c,T2d); LOADB_U(kt + 5, T1a,T1b,T1c,T1d);
    compute(1, 1); VMCNT(36); LGKM_BAR();
    STAGEA_U(kt + 5, 1); WRITEB_U(1, T3a,T3b,T3c,T3d); LOADB_U(kt + 6, T2a,T2b,T2c,T2d);
    compute(2, 0); VMCNT(36); LGKM_BAR();
    STAGEA_U(kt + 6, 2); WRITEB_U(0, T0a,T0b,T0c,T0d); LOADB_U(kt + 7, T3a,T3b,T3c,T3d);
    compute(3, 1); VMCNT(36); LGKM_BAR();
  }
  // epilogue (kt == KT-4): all remaining B already in T1..T3
  STAGEA_U(KT - 1, 3); WRITEB_U(1, T1a,T1b,T1c,T1d);
  compute(0, 0); VMCNT(0); LGKM_BAR();
  WRITEB_U(0, T2a,T2b,T2c,T2d);
  compute(1, 1); LGKM_BAR();
  WRITEB_U(1, T3a,T3b,T3c,T3d);
  compute(2, 0); LGKM_BAR();
  compute(3, 1);

  // epilogue store: silu(g)*u -> bf16. C/D: col=lane&15, row=(lane>>4)*4+r
#pragma unroll
  for (int mf = 0; mf < 2; ++mf) {
#pragma unroll
    for (int r = 0; r < 4; ++r) {
      const int rt = wm + mf * 16 + ((lane >> 4) << 2) + r;
      if (expert && mtile + rt >= cnt) continue;
      const size_t grow = (size_t)((expert ? rowbase : 0) + mtile + rt);
      const int colb = ntile + lrow;
#pragma unroll
      for (int nf = 0; nf < 4; ++nf) {
        float g = accG[mf][nf][r];
        float u = accU[mf][nf][r];
        H[grow * N + colb + nf * 16] = f2bf(g / (1.f + expf(-g)) * u);
      }
    }
  }
#undef STAGEA_U
#undef LOADB_U
#undef WRITEB_U
}

// ================= merged DOWN: Out = A*B.  BM=128, BN=128, BK=32, 256 thr,
// 4 waves (2M x 2N), wave tile 64x64.  Same depth-4 pipeline.
__launch_bounds__(256, 2)
__global__ void moe_dn_k(const short* __restrict__ hbE, const short* __restrict__ hbS,
                         const float* __restrict__ w2, const float* __restrict__ sd,
                         float* __restrict__ pairs, float* __restrict__ outb,
                         const int* __restrict__ counts, const int* __restrict__ offsets,
                         const float* __restrict__ wrow) {
  const int tid = threadIdx.x;
  const int lin = blockIdx.x;
  const short* A; const float* B; float* Out;
  int K, KT, mtile, ntile, rowbase = 0, cnt = 0x7fffffff;
  bool expert;
  if (lin < 20 * 32 * NEXP) {
    int idx = (lin & 7) * 1280 + (lin >> 3);
    int m = idx & 31;
    int rest = idx >> 5;
    int n = rest % 20;
    int e = rest / 20;
    cnt = counts[e];
    mtile = m * 128;
    if (mtile >= cnt) return;
    rowbase = offsets[e];
    A = hbE; B = w2 + (size_t)e * IDIM * HDIM;
    Out = pairs; K = IDIM; KT = IDIM / 32; ntile = n * 128; expert = true;   // KT=52
  } else {
    int s = lin - 20 * 32 * NEXP;
    int n = s % 20;
    int m = s / 20;
    mtile = m * 128;
    A = hbS; B = sd; Out = outb; K = ISDIM; KT = ISDIM / 32; ntile = n * 128; // KT=104
    expert = false;
  }

  __shared__ short Ab[4][128][32];   // 32 KB, linear, 4-deep
  __shared__ short Bb[2][128][32];   // 16 KB, swizzled [n][k]

  f32x4 acc[4][4];
#pragma unroll
  for (int i = 0; i < 4; ++i)
#pragma unroll
    for (int j = 0; j < 4; ++j) { f32x4 z = {0.f,0.f,0.f,0.f}; acc[i][j] = z; }

  int gr0, gr1;
  {
    int r0 = tid >> 2, r1 = (tid >> 2) + 64;
    gr0 = expert ? (rowbase + mtile + r0) : (mtile + r0);
    gr1 = expert ? (rowbase + mtile + r1) : (mtile + r1);
    if (gr0 > NPAIR - 1) gr0 = NPAIR - 1;
    if (gr1 > NPAIR - 1) gr1 = NPAIR - 1;
  }
  const int a_ko = (tid & 3) << 3;
  const short* a_src0 = A + (size_t)gr0 * K + a_ko;
  const short* a_src1 = A + (size_t)gr1 * K + a_ko;

#define STAGEA_D(kt, buf) do { \
    GLDS16(a_src0 + ((kt) << 5), (short*)Ab[buf] + tid * 8); \
    GLDS16(a_src1 + ((kt) << 5), (short*)Ab[buf] + (tid + 256) * 8); \
  } while (0)

  const int b_n  = tid & 127;
  const int b_oh = tid >> 7;
  const float* b_base = B + ntile + b_n;
  const int u0s = (b_oh * 2) ^ ((b_n >> 1) & 3);
  const int u1s = (b_oh * 2 + 1) ^ ((b_n >> 1) & 3);

  f32x4 T0a,T0b,T0c,T0d, T1a,T1b,T1c,T1d, T2a,T2b,T2c,T2d, T3a,T3b,T3c,T3d;

#define LOADB_D(kt, va, vb, vc, vd) do { \
    const float* p_ = b_base + (size_t)((kt) * 32 + b_oh * 16) * HDIM; \
    va[0] = p_[0];                  va[1] = p_[(size_t)1 * HDIM]; \
    va[2] = p_[(size_t)2 * HDIM];   va[3] = p_[(size_t)3 * HDIM]; \
    vb[0] = p_[(size_t)4 * HDIM];   vb[1] = p_[(size_t)5 * HDIM]; \
    vb[2] = p_[(size_t)6 * HDIM];   vb[3] = p_[(size_t)7 * HDIM]; \
    vc[0] = p_[(size_t)8 * HDIM];   vc[1] = p_[(size_t)9 * HDIM]; \
    vc[2] = p_[(size_t)10 * HDIM];  vc[3] = p_[(size_t)11 * HDIM]; \
    vd[0] = p_[(size_t)12 * HDIM];  vd[1] = p_[(size_t)13 * HDIM]; \
    vd[2] = p_[(size_t)14 * HDIM];  vd[3] = p_[(size_t)15 * HDIM]; \
  } while (0)

#define WRITEB_D(buf, va, vb, vc, vd) do { \
    short8v t0_, t1_; \
    t0_[0]=f2bf(va[0]); t0_[1]=f2bf(va[1]); t0_[2]=f2bf(va[2]); t0_[3]=f2bf(va[3]); \
    t0_[4]=f2bf(vb[0]); t0_[5]=f2bf(vb[1]); t0_[6]=f2bf(vb[2]); t0_[7]=f2bf(vb[3]); \
    t1_[0]=f2bf(vc[0]); t1_[1]=f2bf(vc[1]); t1_[2]=f2bf(vc[2]); t1_[3]=f2bf(vc[3]); \
    t1_[4]=f2bf(vd[0]); t1_[5]=f2bf(vd[1]); t1_[6]=f2bf(vd[2]); t1_[7]=f2bf(vd[3]); \
    *reinterpret_cast<short8v*>(&Bb[buf][b_n][u0s << 3]) = t0_; \
    *reinterpret_cast<short8v*>(&Bb[buf][b_n][u1s << 3]) = t1_; \
  } while (0)

  const int lane = tid & 63;
  const int w = tid >> 6;
  const int wm = (w >> 1) * 64;
  const int wn = (w & 1) * 64;
  const int lrow = lane & 15;
  const int lkg = lane >> 4;

  auto compute = [&](int ab, int bb) {
    bf16x8 af[4], bfv[4];
#pragma unroll
    for (int mf = 0; mf < 4; ++mf)
      af[mf] = *reinterpret_cast<const bf16x8*>(&Ab[ab][wm + mf * 16 + lrow][lkg << 3]);
#pragma unroll
    for (int nf = 0; nf < 4; ++nf) {
      const int n = wn + nf * 16 + lrow;
      const int kg = (lkg ^ ((n >> 1) & 3)) << 3;
      bfv[nf] = *reinterpret_cast<const bf16x8*>(&Bb[bb][n][kg]);
    }
#pragma unroll
    for (int mf = 0; mf < 4; ++mf)
#pragma unroll
      for (int nf = 0; nf < 4; ++nf)
        acc[mf][nf] = __builtin_amdgcn_mfma_f32_16x16x32_bf16(af[mf], bfv[nf], acc[mf][nf], 0, 0, 0);
  };

  STAGEA_D(0, 0); STAGEA_D(1, 1); STAGEA_D(2, 2);
  LOADB_D(0, T0a,T0b,T0c,T0d);
  LOADB_D(1, T1a,T1b,T1c,T1d);
  LOADB_D(2, T2a,T2b,T2c,T2d);
  LOADB_D(3, T3a,T3b,T3c,T3d);
  WRITEB_D(0, T0a,T0b,T0c,T0d);
  VMCNT(0);
  LGKM_BAR();

  int kt = 0;
  for (; kt < KT - 4; kt += 4) {
    STAGEA_D(kt + 3, 3); WRITEB_D(1, T1a,T1b,T1c,T1d); LOADB_D(kt + 4, T0a,T0b,T0c,T0d);
    compute(0, 0); VMCNT(36); LGKM_BAR();
    STAGEA_D(kt + 4, 0); WRITEB_D(0, T2a,T2b,T2c,T2d); LOADB_D(kt + 5, T1a,T1b,T1c,T1d);
    compute(1, 1); VMCNT(36); LGKM_BAR();
    STAGEA_D(kt + 5, 1); WRITEB_D(1, T3a,T3b,T3c,T3d); LOADB_D(kt + 6, T2a,T2b,T2c,T2d);
    compute(2, 0); VMCNT(36); LGKM_BAR();
    STAGEA_D(kt + 6, 2); WRITEB_D(0, T0a,T0b,T0c,T0d); LOADB_D(kt + 7, T3a,T3b,T3c,T3d);
    compute(3, 1); VMCNT(36); LGKM_BAR();
  }
  STAGEA_D(KT - 1, 3); WRITEB_D(1, T1a,T1b,T1c,T1d);
  compute(0, 0); VMCNT(0); LGKM_BAR();
  WRITEB_D(0, T2a,T2b,T2c,T2d);
  compute(1, 1); LGKM_BAR();
  WRITEB_D(1, T3a,T3b,T3c,T3d);
  compute(2, 0); LGKM_BAR();
  compute(3, 1);

#pragma unroll
  for (int mf = 0; mf < 4; ++mf) {
#pragma unroll
    for (int r = 0; r < 4; ++r) {
      const int rt = wm + mf * 16 + ((lane >> 4) << 2) + r;
      const int colb = ntile + wn + lrow;
      if (expert) {
        if (mtile + rt < cnt) {
          const int gr = rowbase + mtile + rt;
          const float sc = wrow[gr];
          float* o = Out + (size_t)gr * HDIM + colb;
#pragma unroll
          for (int nf = 0; nf < 4; ++nf) o[nf * 16] = sc * acc[mf][nf][r];
        }
      } else {
        float* o = Out + (size_t)(mtile + rt) * HDIM + colb;
#pragma unroll
        for (int nf = 0; nf < 4; ++nf) o[nf * 16] = acc[mf][nf][r];
      }
    }
  }
#undef STAGEA_D
#undef LOADB_D
#undef WRITEB_D
}

// ---------------- final combine: out[t] += pairs[g0] + pairs[g1]
__global__ void combine_kernel(float* __restrict__ out, const float* __restrict__ pairs,
                               const int* __restrict__ pairpos) {
  const int t = blockIdx.x;
  const int g0 = pairpos[t * 2], g1 = pairpos[t * 2 + 1];
  const f32x4* p0 = (const f32x4*)(pairs + (size_t)g0 * HDIM);
  const f32x4* p1 = (const f32x4*)(pairs + (size_t)g1 * HDIM);
  f32x4* o = (f32x4*)(out + (size_t)t * HDIM);
  for (int c = threadIdx.x; c < HDIM / 4; c += 256)
    o[c] = o[c] + p0[c] + p1[c];
}

extern "C" void kernel_launch(void* const* d_in, const int* in_sizes, int n_in,
                              void* d_out, int out_size, void* d_ws, size_t ws_size,
                              hipStream_t stream) {
  const float* x  = (const float*)d_in[0];
  const float* rw = (const float*)d_in[1];
  const float* w1 = (const float*)d_in[2];
  const float* w3 = (const float*)d_in[3];
  const float* w2 = (const float*)d_in[4];
  const float* sg = (const float*)d_in[5];
  const float* su = (const float*)d_in[6];
  const float* sd = (const float*)d_in[7];
  float* out = (float*)d_out;
  (void)in_sizes; (void)n_in; (void)out_size; (void)ws_size;

  char* ws = (char*)d_ws;
  size_t off = 0;
  auto alloc = [&](size_t bytes) -> void* {
    void* p = ws + off;
    off = (off + bytes + 255) & ~(size_t)255;
    return p;
  };
  int*   counts  = (int*)alloc(NEXP * 4);          // @0
  int*   slotc   = (int*)alloc(NEXP * 4);          // @256
  int*   offsets = (int*)alloc(NEXP * 4);
  int*   tidx    = (int*)alloc(NPAIR * 4);
  float* tw      = (float*)alloc(NPAIR * 4);
  float* wrowv   = (float*)alloc(NPAIR * 4);
  int*   pairpos = (int*)alloc(NPAIR * 4);
  short* xb      = (short*)alloc((size_t)TOKENS * HDIM * 2);
  short* xg      = (short*)alloc((size_t)NPAIR * HDIM * 2);
  short* hbE     = (short*)alloc((size_t)NPAIR * IDIM * 2);
  short* hbS     = (short*)alloc((size_t)TOKENS * ISDIM * 2);
  float* pairs   = (float*)alloc((size_t)NPAIR * HDIM * 4);

  hipMemsetAsync(d_ws, 0, 512, stream);  // zero counts + slotc

  router_kernel<<<dim3(TOKENS), dim3(64), 0, stream>>>(x, rw, counts, tidx, tw);
  scan_kernel<<<dim3(1), dim3(64), 0, stream>>>(counts, offsets);
  gather_kernel<<<dim3(TOKENS), dim3(256), 0, stream>>>(x, tidx, tw, offsets, slotc,
                                                        pairpos, wrowv, xb, xg);

  // merged up: experts (32m x 26n x 16e = 13312) + shared (832)
  moe_up_k<<<dim3(26 * 32 * NEXP + 832), dim3(256), 0, stream>>>(
      xg, xb, w1, w3, sg, su, hbE, hbS, counts, offsets);

  // merged down: experts (32m x 20n x 16e = 10240) + shared (320)
  moe_dn_k<<<dim3(20 * 32 * NEXP + 320), dim3(256), 0, stream>>>(
      hbE, hbS, w2, sd, pairs, out, counts, offsets, wrowv);

  combine_kernel<<<dim3(TOKENS), dim3(256), 0, stream>>>(out, pairs, pairpos);
}